// Round 11
// baseline (339.044 us; speedup 1.0000x reference)
//
#include <hip/hip_runtime.h>

typedef __bf16 bf16;
typedef __bf16 bf16x4 __attribute__((ext_vector_type(4)));
typedef __bf16 bf16x8 __attribute__((ext_vector_type(8)));
typedef float f32x4 __attribute__((ext_vector_type(4)));

#define N_TOK 2048
#define M_TOK 2048
#define DIM 1024
#define CDIM 768
#define DFF 4096

// async global->LDS, 16B per lane; LDS dest = wave-uniform base + lane*16
static __device__ __forceinline__ void async16(const void* g, void* l) {
  __builtin_amdgcn_global_load_lds((const __attribute__((address_space(1))) void*)g,
                                   (__attribute__((address_space(3))) void*)l, 16, 0, 0);
}

// ---------- shared device helpers ----------
// local dtype detect: low-16 halves of first 512 words plausible as bf16?
__device__ __forceinline__ bool detect_bf(const void* xprobe, float* sbuf) {
  int* cnt = (int*)sbuf;
  if (threadIdx.x == 0) *cnt = 0;
  __syncthreads();
  const unsigned* w = (const unsigned*)xprobe;
  int ok = 0;
  for (int i = threadIdx.x; i < 512; i += 256) {
    unsigned lo = w[i] & 0xFFFFu;
    float f = __uint_as_float(lo << 16);
    if (lo == 0u || (fabsf(f) > 1e-3f && fabsf(f) < 1e3f)) ok++;
  }
  atomicAdd(cnt, ok);
  __syncthreads();
  return *cnt >= 256;
}

// 32x32 transpose tile (256 active thr); explicit block coords (bx, by)
__device__ __forceinline__ void t32(int bx, int by, const void* in, bf16* out,
                                    int r0, int Rcnt, int c0, int Cfull,
                                    bool isbf, bf16* t) {
  const int cb = bx * 32, rb = by * 32;
  const int tx = threadIdx.x & 31, ty = threadIdx.x >> 5;
#pragma unroll
  for (int i = 0; i < 4; i++) {
    const size_t r = (size_t)(r0 + rb + ty + i * 8);
    const size_t c = (size_t)(c0 + cb + tx);
    float v = isbf ? (float)((const bf16*)in)[r * Cfull + c]
                   : ((const float*)in)[r * Cfull + c];
    t[(ty + i * 8) * 33 + tx] = (bf16)v;
  }
  __syncthreads();
#pragma unroll
  for (int i = 0; i < 4; i++)
    out[(size_t)(cb + ty + i * 8) * Rcnt + rb + tx] = t[tx * 33 + ty + i * 8];
}

// LayerNorm one row, single global read (row staged in LDS floats).
__device__ __forceinline__ void ln_row(const void* x, const void* wr, const void* br,
                                       bf16* outp, int cols, int row,
                                       bool in_bf, bool w_bf,
                                       float* xrow, float* sh) {
  const bf16* xr_b = (const bf16*)x + (size_t)row * cols;
  const float* xr_f = (const float*)x + (size_t)row * cols;
  bf16* orow = outp + (size_t)row * cols;
  float s = 0.f, ss = 0.f;
  for (int c = threadIdx.x; c < cols; c += 256) {
    float v = in_bf ? (float)xr_b[c] : xr_f[c];
    xrow[c] = v;
    s += v; ss += v * v;
  }
  for (int d = 1; d < 64; d <<= 1) { s += __shfl_xor(s, d, 64); ss += __shfl_xor(ss, d, 64); }
  const int wv = threadIdx.x >> 6, lane = threadIdx.x & 63;
  if (lane == 0) { sh[wv] = s; sh[4 + wv] = ss; }
  __syncthreads();
  s = sh[0] + sh[1] + sh[2] + sh[3];
  ss = sh[4] + sh[5] + sh[6] + sh[7];
  const float mean = s / cols;
  float var = ss / cols - mean * mean;
  var = fmaxf(var, 0.f);
  const float r = rsqrtf(var + 1e-12f);
  for (int c = threadIdx.x; c < cols; c += 256) {
    const float wv2 = w_bf ? (float)((const bf16*)wr)[c] : ((const float*)wr)[c];
    const float bv2 = w_bf ? (float)((const bf16*)br)[c] : ((const float*)br)[c];
    orow[c] = (bf16)((xrow[c] - mean) * r * wv2 + bv2);
  }
}

// ---------------- prep: z0-3 attn-weight transposes, z4-7 input LNs, z8 conv --
struct PrepArgs {
  const void* tsrc[4]; bf16* tdst[4]; int tRcnt[4], tCfull[4], tgy[4];
  const void* x; const void* qnw; const void* qnb; bf16* xq;
  const void* ctx; const void* kvnw; const void* kvnb; bf16* kvn;
  const void* csrc[12]; bf16* cdst[12]; int cn[12];
  const void* xprobe;
};
__global__ __launch_bounds__(256) void prep_kernel(PrepArgs a, int* flag) {
  __shared__ __align__(16) float sbuf[1040];  // union: bf16 t[32*33] | xrow+sh
  const int z = blockIdx.z;
  const bool isbf = detect_bf(a.xprobe, sbuf);
  if (z < 4) {
    if ((int)blockIdx.y >= a.tgy[z]) return;
    t32(blockIdx.x, blockIdx.y, a.tsrc[z], a.tdst[z], 0, a.tRcnt[z], 0, a.tCfull[z],
        isbf, (bf16*)sbuf);
  } else if (z < 8) {
    const int row = blockIdx.x + 32 * blockIdx.y + (z & 1) * 1024;
    if (z < 6) ln_row(a.x,   a.qnw,  a.qnb,  a.xq,  DIM,  row, isbf, isbf, sbuf, sbuf + 1024);
    else       ln_row(a.ctx, a.kvnw, a.kvnb, a.kvn, CDIM, row, isbf, isbf, sbuf, sbuf + 1024);
  } else {
    const int b = blockIdx.x + 32 * blockIdx.y;
    if (b == 0 && threadIdx.x == 0) *flag = isbf ? 1 : 0;
    if (b >= 12) return;
    const void* in = a.csrc[b];
    bf16* out = a.cdst[b];
    const int n = a.cn[b];
    for (int i = threadIdx.x; i < n; i += 256)
      out[i] = isbf ? ((const bf16*)in)[i] : (bf16)((const float*)in)[i];
  }
}

// ---------------- post: z0 w2-h0 T (remapped 32x64), z1 post-norm LN ----------
struct PostArgs {
  const void* w2; bf16* w2T;
  const bf16* xat; const void* pnw; const void* pnb; bf16* hln;
};
__global__ __launch_bounds__(256) void post_kernel(PostArgs a, const int* flag) {
  __shared__ __align__(16) float sbuf[1040];
  const bool isbf = (*flag != 0);
  if (blockIdx.z == 0) {  // w2[0:2048, :] -> w2T [1024][2048]; 32 x 64 via remap
    const int tbx = blockIdx.x & 31, tby = blockIdx.y + 32 * (blockIdx.x >> 5);
    t32(tbx, tby, a.w2, a.w2T, 0, 2048, 0, DIM, isbf, (bf16*)sbuf);
  } else {  // post-norm LN over 2048 rows (input bf16, weights raw)
    const int row = blockIdx.x + 64 * blockIdx.y;
    ln_row(a.xat, a.pnw, a.pnb, a.hln, DIM, row, true, isbf, sbuf, sbuf + 1024);
  }
}

__device__ __forceinline__ float gelu_f(float x) {
  float u = 0.7978845608028654f * (x + 0.044715f * x * x * x);
  return 0.5f * x * (1.f + tanhf(u));
}

// ------ shared epilogue for the 64x64 gemm bodies ------
template <int EPI>
__device__ __forceinline__ void gemm_epi(
    f32x4 (&acc)[2][2], int row0, int col0, int wr, int wc, int lq, int lm,
    const bf16* bias, const void* resid, void* Cout, int ldc, const int* flag) {
  const bool isbf = (*flag != 0);
#pragma unroll
  for (int i = 0; i < 2; i++) {
    const int rb = row0 + wr + i * 16 + lq * 4;
#pragma unroll
    for (int j = 0; j < 2; j++) {
      const int c = col0 + wc + j * 16 + lm;
      const float bv = (EPI != 5) ? (float)bias[c] : 0.f;
#pragma unroll
      for (int rg = 0; rg < 4; rg++) {
        const size_t idx = (size_t)(rb + rg) * ldc + c;
        float v = acc[i][j][rg] + bv;
        if (EPI == 1)
          v += isbf ? (float)((const bf16*)resid)[idx] : ((const float*)resid)[idx];
        if (EPI == 2) v = gelu_f(v);
        if (EPI == 4) v += (float)((const bf16*)resid)[idx];
        if (EPI == 5)
          v += isbf ? (float)((bf16*)Cout)[idx] : ((float*)Cout)[idx];
        if (EPI == 4 || EPI == 5) {
          if (isbf) ((bf16*)Cout)[idx] = (bf16)v;
          else      ((float*)Cout)[idx] = v;
        } else {
          ((bf16*)Cout)[idx] = (bf16)v;
        }
      }
    }
  }
}

// -------- gemm_body: 64x64 tile, BK=64, 256 thr (4 waves 2x2, 32x32/wave) ------
// Harness-verified (rounds 4-10): 2-phase double-buffer + both-sides XOR swizzle.
// (BK=128 variant tried r9: REGRESSED -- 64KB LDS halves blocks/CU; m132 lesson.)
template <int EPI>
__device__ __forceinline__ void gemm_body(
    int bx, int by,
    const bf16* __restrict__ A, const bf16* __restrict__ Bt,
    const bf16* __restrict__ bias, const void* __restrict__ resid,
    void* __restrict__ Cout, int K, int ldc, const int* flag) {
  __shared__ __align__(16) bf16 As[2][64 * 64];
  __shared__ __align__(16) bf16 Bs[2][64 * 64];
  const int tid = threadIdx.x;
  const int lane = tid & 63, wv = tid >> 6;
  const int lq = lane >> 4, lm = lane & 15;
  const int row0 = by * 64, col0 = bx * 64;
  const int wr = (wv >> 1) * 32, wc = (wv & 1) * 32;

  const int sr = lane >> 3;              // staging row within 8-row group
  const int sc = ((lane & 7) ^ sr) * 8;  // pre-swizzled source col (elems)
  const int swz = (lm & 7) << 3;         // read-side XOR (elems)

  f32x4 acc[2][2] = {};

  const bf16* Abase = A + (size_t)(row0 + wv * 16 + sr) * K + sc;
  const bf16* Bbase = Bt + (size_t)(col0 + wv * 16 + sr) * K + sc;

  const int nt = K >> 6;
#pragma unroll
  for (int b = 0; b < 2; b++) {
    async16(Abase + (size_t)(b * 8) * K, &As[0][wv * 1024 + b * 512]);
    async16(Bbase + (size_t)(b * 8) * K, &Bs[0][wv * 1024 + b * 512]);
  }
  __syncthreads();

  int cur = 0;
  for (int t = 0; t < nt; ++t) {
    if (t + 1 < nt) {  // prefetch next tile; loads fly under the MFMA phase
      const int k1 = (t + 1) << 6;
#pragma unroll
      for (int b = 0; b < 2; b++) {
        async16(Abase + (size_t)(b * 8) * K + k1, &As[cur ^ 1][wv * 1024 + b * 512]);
        async16(Bbase + (size_t)(b * 8) * K + k1, &Bs[cur ^ 1][wv * 1024 + b * 512]);
      }
    }
#pragma unroll
    for (int kh = 0; kh < 2; kh++) {
      const int cofs = (kh * 32 + lq * 8) ^ swz;
      bf16x8 af[2], bfv[2];
#pragma unroll
      for (int i = 0; i < 2; i++)
        af[i] = *(const bf16x8*)&As[cur][(wr + i * 16 + lm) * 64 + cofs];
#pragma unroll
      for (int j = 0; j < 2; j++)
        bfv[j] = *(const bf16x8*)&Bs[cur][(wc + j * 16 + lm) * 64 + cofs];
#pragma unroll
      for (int i = 0; i < 2; i++)
#pragma unroll
        for (int j = 0; j < 2; j++)
          acc[i][j] = __builtin_amdgcn_mfma_f32_16x16x32_bf16(af[i], bfv[j], acc[i][j], 0, 0, 0);
    }
    __syncthreads();  // drains prefetch vmcnt + this tile's lgkm reads
    cur ^= 1;
  }
  gemm_epi<EPI>(acc, row0, col0, wr, wc, lq, lm, bias, resid, Cout, ldc, flag);
}

// T1 XCD swizzle: contiguous grid chunks per XCD (all grids have nwg % 8 == 0)
template <int EPI>
__global__ __launch_bounds__(256) void gemm64db(
    const bf16* __restrict__ A, const bf16* __restrict__ Bt,
    const bf16* __restrict__ bias, const void* __restrict__ resid,
    void* __restrict__ Cout, int K, int ldc, const int* flag) {
  const int gx = gridDim.x;
  const int nwg = gx * gridDim.y;
  const int fid = blockIdx.x + gx * blockIdx.y;
  const int sid = (fid & 7) * (nwg >> 3) + (fid >> 3);
  gemm_body<EPI>(sid % gx, sid / gx, A, Bt, bias, resid, Cout, K, ldc, flag);
}

// ---- o-projection with FUSED attention combine: A = (pO0+pO1)*rinv ----------
// K-chunks are 64-wide and head-aligned (k0 % 64 == 0 -> one head per chunk),
// so rinv = 1/(l0[h][n]+l1[h][n]) is constant per staged row-chunk. A is
// reg-staged T14-style: pO0/pO1/l loads for tile t+1 issued BEFORE compute,
// cvt+scale+ds_write AFTER compute into the inactive buffer (end-of-iter
// __syncthreads drains lgkm + B-side vmcnt). Lane writes LDS elem
// wv*1024+b*512+lane*8 (same linear spot async16 wrote) holding global col
// ((lane&7)^sr)*8 -- identical both-sides mapping, numerics identical to the
// old combine->om->gemm path. B (woT) stays global_load_lds. EPI 1 epilogue.
struct OprojArgs {
  const bf16* pO0; const bf16* pO1; const float* l0; const float* l1;
  const bf16* Bt; const bf16* bias; const void* resid; void* Cout;
};
__global__ __launch_bounds__(256) void oproj_fused(OprojArgs a, const int* flag) {
  __shared__ __align__(16) bf16 As[2][64 * 64];
  __shared__ __align__(16) bf16 Bs[2][64 * 64];
  const int fid = blockIdx.x + 16 * blockIdx.y;  // grid (16,32) = 512
  const int sid = (fid & 7) * 64 + (fid >> 3);
  const int bx = sid & 15, by = sid >> 4;
  const int tid = threadIdx.x;
  const int lane = tid & 63, wv = tid >> 6;
  const int lq = lane >> 4, lm = lane & 15;
  const int row0 = by * 64, col0 = bx * 64;
  const int wr = (wv >> 1) * 32, wc = (wv & 1) * 32;

  const int sr = lane >> 3;
  const int sc = ((lane & 7) ^ sr) * 8;
  const int swz = (lm & 7) << 3;

  f32x4 acc[2][2] = {};

  const bf16* Bbase = a.Bt + (size_t)(col0 + wv * 16 + sr) * DIM + sc;
  const int n0r = row0 + wv * 16 + sr;  // b=0 staged row (token)

  bf16x8 p0[2], p1[2];
  float rv[2];
  // prologue: tile 0 (k0 = 0, head 0)
#pragma unroll
  for (int b = 0; b < 2; b++) {
    const int n = n0r + b * 8;
    p0[b] = *(const bf16x8*)&a.pO0[(size_t)n * DIM + sc];
    p1[b] = *(const bf16x8*)&a.pO1[(size_t)n * DIM + sc];
    rv[b] = 1.f / (a.l0[n] + a.l1[n]);
    async16(Bbase + (size_t)(b * 8) * DIM, &Bs[0][wv * 1024 + b * 512]);
  }
#pragma unroll
  for (int b = 0; b < 2; b++) {
    bf16x8 w;
#pragma unroll
    for (int e = 0; e < 8; e++)
      w[e] = (bf16)(((float)p0[b][e] + (float)p1[b][e]) * rv[b]);
    *(bf16x8*)&As[0][wv * 1024 + b * 512 + lane * 8] = w;
  }
  __syncthreads();

  int cur = 0;
  for (int t = 0; t < 16; ++t) {
    const bool pf = (t + 1 < 16);
    if (pf) {  // issue next tile's loads; they fly under compute
      const int k1 = (t + 1) << 6;
      const int h1 = t + 1;  // head = k/64
#pragma unroll
      for (int b = 0; b < 2; b++) {
        const int n = n0r + b * 8;
        p0[b] = *(const bf16x8*)&a.pO0[(size_t)n * DIM + k1 + sc];
        p1[b] = *(const bf16x8*)&a.pO1[(size_t)n * DIM + k1 + sc];
        rv[b] = 1.f / (a.l0[h1 * N_TOK + n] + a.l1[h1 * N_TOK + n]);
        async16(Bbase + (size_t)(b * 8) * DIM + k1, &Bs[cur ^ 1][wv * 1024 + b * 512]);
      }
    }
#pragma unroll
    for (int kh = 0; kh < 2; kh++) {
      const int cofs = (kh * 32 + lq * 8) ^ swz;
      bf16x8 af[2], bfv[2];
#pragma unroll
      for (int i = 0; i < 2; i++)
        af[i] = *(const bf16x8*)&As[cur][(wr + i * 16 + lm) * 64 + cofs];
#pragma unroll
      for (int j = 0; j < 2; j++)
        bfv[j] = *(const bf16x8*)&Bs[cur][(wc + j * 16 + lm) * 64 + cofs];
#pragma unroll
      for (int i = 0; i < 2; i++)
#pragma unroll
        for (int j = 0; j < 2; j++)
          acc[i][j] = __builtin_amdgcn_mfma_f32_16x16x32_bf16(af[i], bfv[j], acc[i][j], 0, 0, 0);
    }
    if (pf) {  // normalize + write next A tile into inactive buffer
#pragma unroll
      for (int b = 0; b < 2; b++) {
        bf16x8 w;
#pragma unroll
        for (int e = 0; e < 8; e++)
          w[e] = (bf16)(((float)p0[b][e] + (float)p1[b][e]) * rv[b]);
        *(bf16x8*)&As[cur ^ 1][wv * 1024 + b * 512 + lane * 8] = w;
      }
    }
    __syncthreads();  // drains A ds_writes (lgkm) + B async16 (vmcnt)
    cur ^= 1;
  }
  gemm_epi<1>(acc, row0, col0, wr, wc, lq, lm, a.bias, a.resid, a.Cout, DIM, flag);
}

// ---- fused MLP2-h0 gemm + MLP-h1 weight transposes (grid 64x32x3) ----
// z0: gemm<4> (bx<16, XCD-swizzled). z1: w1[:,2048:4096]->w1T (w1T free: its
// reader MLP1-h0 already done). z2: w2[2048:,:]->w2Ts SHADOW, 32x64 via remap.
struct Mlp2Args {
  const bf16* h1; const bf16* w2T; const bf16* b2; const bf16* xat; void* out;
  const void* w1raw; bf16* w1Tdst;
  const void* w2raw; bf16* w2Tdst;
};
__global__ __launch_bounds__(256) void mlp2h0_fused(Mlp2Args a, const int* flag) {
  const int z = blockIdx.z;
  if (z == 0) {
    if ((int)blockIdx.x >= 16) return;
    const int fid = blockIdx.x + 16 * blockIdx.y;  // 512 blocks
    const int sid = (fid & 7) * 64 + (fid >> 3);
    gemm_body<4>(sid & 15, sid >> 4, a.h1, a.w2T, a.b2, a.xat, a.out,
                 2048, DIM, flag);
  } else {
    __shared__ __align__(16) bf16 t[32 * 33];
    const bool isbf = (*flag != 0);
    if (z == 1) {
      t32(blockIdx.x, blockIdx.y, a.w1raw, a.w1Tdst, 0, DIM, 2048, DFF, isbf, t);
    } else {
      const int tbx = blockIdx.x & 31, tby = blockIdx.y + 32 * (blockIdx.x >> 5);
      t32(tbx, tby, a.w2raw, a.w2Tdst, 2048, 2048, 0, DIM, isbf, t);
    }
  }
}

// ------- fused q/k/v projection, z=2 computes V^T directly (bias per row) ------
struct QkvArgs {
  const bf16* A[3];
  const bf16* Bt[3];
  const bf16* bias[3];
  bf16* C[3];
  int K[3], ldc[3], brow[3];
};
__global__ __launch_bounds__(256) void gemm64db_qkv(QkvArgs a) {
  const int z = blockIdx.z;
  int gx, bx0, by0;
  if (z < 2) { gx = 16; bx0 = blockIdx.y; by0 = blockIdx.x; }   // 16c x 32r
  else       { gx = 32; bx0 = blockIdx.x; by0 = blockIdx.y; }   // 32c x 16r
  const int fid = bx0 + gx * by0;                                // 512 blocks
  const int sid = (fid & 7) * 64 + (fid >> 3);
  const int bx = sid % gx, by = sid / gx;
  const bf16* A = a.A[z];
  const bf16* Bt = a.Bt[z];
  const int K = a.K[z];
  __shared__ __align__(16) bf16 As[2][64 * 64];
  __shared__ __align__(16) bf16 Bs[2][64 * 64];
  const int tid = threadIdx.x;
  const int lane = tid & 63, wv = tid >> 6;
  const int lq = lane >> 4, lm = lane & 15;
  const int row0 = by * 64, col0 = bx * 64;
  const int wr = (wv >> 1) * 32, wc = (wv & 1) * 32;

  const int sr = lane >> 3;
  const int sc = ((lane & 7) ^ sr) * 8;
  const int swz = (lm & 7) << 3;

  f32x4 acc[2][2] = {};

  const bf16* Abase = A + (size_t)(row0 + wv * 16 + sr) * K + sc;
  const bf16* Bbase = Bt + (size_t)(col0 + wv * 16 + sr) * K + sc;

  const int nt = K >> 6;
#pragma unroll
  for (int b = 0; b < 2; b++) {
    async16(Abase + (size_t)(b * 8) * K, &As[0][wv * 1024 + b * 512]);
    async16(Bbase + (size_t)(b * 8) * K, &Bs[0][wv * 1024 + b * 512]);
  }
  __syncthreads();

  int cur = 0;
  for (int t = 0; t < nt; ++t) {
    if (t + 1 < nt) {
      const int k1 = (t + 1) << 6;
#pragma unroll
      for (int b = 0; b < 2; b++) {
        async16(Abase + (size_t)(b * 8) * K + k1, &As[cur ^ 1][wv * 1024 + b * 512]);
        async16(Bbase + (size_t)(b * 8) * K + k1, &Bs[cur ^ 1][wv * 1024 + b * 512]);
      }
    }
#pragma unroll
    for (int kh = 0; kh < 2; kh++) {
      const int cofs = (kh * 32 + lq * 8) ^ swz;
      bf16x8 af[2], bfv[2];
#pragma unroll
      for (int i = 0; i < 2; i++)
        af[i] = *(const bf16x8*)&As[cur][(wr + i * 16 + lm) * 64 + cofs];
#pragma unroll
      for (int j = 0; j < 2; j++)
        bfv[j] = *(const bf16x8*)&Bs[cur][(wc + j * 16 + lm) * 64 + cofs];
#pragma unroll
      for (int i = 0; i < 2; i++)
#pragma unroll
        for (int j = 0; j < 2; j++)
          acc[i][j] = __builtin_amdgcn_mfma_f32_16x16x32_bf16(af[i], bfv[j], acc[i][j], 0, 0, 0);
    }
    __syncthreads();
    cur ^= 1;
  }

  const bf16* bias = a.bias[z];
  bf16* C = a.C[z];
  const int ldc = a.ldc[z];
  const bool brow = a.brow[z] != 0;
#pragma unroll
  for (int i = 0; i < 2; i++) {
    const int rb = row0 + wr + i * 16 + lq * 4;
#pragma unroll
    for (int j = 0; j < 2; j++) {
      const int c = col0 + wc + j * 16 + lm;
      const float bcol = brow ? 0.f : (float)bias[c];
#pragma unroll
      for (int rg = 0; rg < 4; rg++) {
        const float bv = brow ? (float)bias[rb + rg] : bcol;
        C[(size_t)(rb + rg) * ldc + c] = (bf16)(acc[i][j][rg] + bv);
      }
    }
  }
}

// ---------------- Flash attention v13: global_load_lds staging ----------------
// K/V staged via async16 (zero VALU round-trip): linear LDS dest + pre-swizzled
// per-lane SOURCE col (both-sides rule). Verified r9/r10.
// z0,z1: attention halves. z2..9: w1-h0 transpose (aliases KPs).
__global__ __launch_bounds__(512) void attn_kernel(
    const bf16* __restrict__ q, const bf16* __restrict__ k,
    const bf16* __restrict__ vT, bf16* __restrict__ pO0, bf16* __restrict__ pO1,
    float* __restrict__ l0, float* __restrict__ l1,
    const void* __restrict__ w1raw, bf16* __restrict__ w1Tdst,
    const int* __restrict__ flag) {
  __shared__ __align__(16) bf16 KPs[128 * 128];  // Ks [128][64]; then P^T [128][128]
  __shared__ __align__(16) bf16 Vs[64 * 128];    // [d 64][m 128]
  const int z = blockIdx.z;
  if (z >= 2) {  // w1-h0 transpose: 2048 blocks over z=2..9
    if (threadIdx.x >= 256) return;  // waves 4-7 exit (wave-aligned)
    const int id = blockIdx.x + 16 * blockIdx.y + 256 * (z - 2);
    const bool isbf = (*flag != 0);
    t32(id & 63, id >> 6, w1raw, w1Tdst, 0, DIM, 0, DFF, isbf, (bf16*)KPs);
    return;
  }
  const int tid = threadIdx.x, lane = tid & 63, wv = tid >> 6;
  const int lq = lane >> 4, lm = lane & 15;
  // XCD-aware bijective swizzle (512 = 8*64): XCD j gets 4 whole heads (1 half).
  const int fid = blockIdx.x + 16 * (blockIdx.y + 16 * z);
  const int sid = (fid & 7) * 64 + (fid >> 3);
  const int n0 = (sid & 15) * 128;
  const int h = (sid >> 4) & 15;
  const int half = sid >> 8;
  const int mbeg = half * (M_TOK / 2), mend = mbeg + M_TOK / 2;
  bf16* pO = half ? pO1 : pO0;
  float* lb = half ? l1 : l0;

  bf16x8 qf[2];
#pragma unroll
  for (int f = 0; f < 2; f++)
    qf[f] = *(const bf16x8*)&q[(size_t)(n0 + wv * 16 + lm) * DIM + h * 64 + f * 32 + lq * 8];

  f32x4 oacc[4] = {};  // O^T tiles: rows d, cols n (n-col = wv*16+lm)
  float lsum = 0.f;
  const float sc = 0.125f * 1.4426950408889634f;  // (1/sqrt(64)) * log2(e)

  // per-lane pre-swizzled staging sources (loop-invariant)
  const int l3 = lane >> 3, l4 = lane >> 4;
  const bf16* kb = k + (size_t)(wv * 16 + l3) * DIM + h * 64 + (((lane & 7) ^ l3) << 3);
  const bf16* vb0 = vT + (size_t)(h * 64 + wv * 8 + l4) * M_TOK + (((lane & 15) ^ l4) << 3);
  const bf16* vb1 = vT + (size_t)(h * 64 + wv * 8 + 4 + l4) * M_TOK + (((lane & 15) ^ (4 + l4)) << 3);
  bf16* kd = KPs + wv * 1024;  // wave-uniform dest (rows wv*16..+16 of [128][64])
  bf16* vd = Vs + wv * 1024;   // rows wv*8..+8 of [64][128]

  for (int m0 = mbeg; m0 < mend; m0 += 128) {
    __syncthreads();  // prev tile fully consumed (P^T + V PV reads done)
    {
      const bf16* kt = kb + (size_t)m0 * DIM;
      async16(kt, kd);
      async16(kt + (size_t)8 * DIM, kd + 512);
      async16(vb0 + m0, vd);
      async16(vb1 + m0, vd + 512);
    }
    __syncthreads();  // drains vmcnt(0) -> tile visible in LDS

    // S^T into regs: tile j rows m = j*16+lq*4+rg, col n = wv*16 + lm
    f32x4 s[8];
    __builtin_amdgcn_s_setprio(1);
#pragma unroll
    for (int j = 0; j < 8; j++) {
      const int kswz = (lm & 7) << 3;  // row = j*16+lm -> row&7 = lm&7
      bf16x8 kf0 = *(const bf16x8*)&KPs[(j * 16 + lm) * 64 + ((lq * 8) ^ kswz)];
      bf16x8 kf1 = *(const bf16x8*)&KPs[(j * 16 + lm) * 64 + ((32 + lq * 8) ^ kswz)];
      f32x4 zz = {};
      zz = __builtin_amdgcn_mfma_f32_16x16x32_bf16(kf0, qf[0], zz, 0, 0, 0);
      s[j] = __builtin_amdgcn_mfma_f32_16x16x32_bf16(kf1, qf[1], zz, 0, 0, 0);
    }
    __builtin_amdgcn_s_setprio(0);
    asm volatile("s_waitcnt lgkmcnt(0)" ::: "memory");
    __builtin_amdgcn_s_barrier();  // Ks region free -> becomes P^T [128][128]

#pragma unroll
    for (int j = 0; j < 8; j++) {
      bf16x4 pw;
#pragma unroll
      for (int rg = 0; rg < 4; rg++) {
        const float pv = exp2f(s[j][rg] * sc);
        lsum += pv;
        pw[rg] = (bf16)pv;
      }
      // P^T row n = wv*16+lm (row&7 = lm&7), col m = j*16+lq*4; swizzled write
      *(bf16x4*)&KPs[(wv * 16 + lm) * 128 + ((j * 16 + lq * 4) ^ ((lm & 7) << 3))] = pw;
    }

    // O^T += V^T P^T (pf rows are this wave's own -> same-wave RAW, lgkmcnt)
    __builtin_amdgcn_s_setprio(1);
#pragma unroll
    for (int kk = 0; kk < 4; kk++) {
      bf16x8 pf = *(const bf16x8*)&KPs[(wv * 16 + lm) * 128 +
                                       ((kk * 32 + lq * 8) ^ ((lm & 7) << 3))];
#pragma unroll
      for (int dt = 0; dt < 4; dt++) {
        bf16x8 vf = *(const bf16x8*)&Vs[(dt * 16 + lm) * 128 +
                                        ((kk * 32 + lq * 8) ^ ((lm & 7) << 3))];
        oacc[dt] = __builtin_amdgcn_mfma_f32_16x16x32_bf16(vf, pf, oacc[dt], 0, 0, 0);
      }
    }
    __builtin_amdgcn_s_setprio(0);
  }

  // partial row-sum: reduce over the 4 lanes sharing this n (lane bits 4..5)
  lsum += __shfl_xor(lsum, 16, 64);
  lsum += __shfl_xor(lsum, 32, 64);
  if (lane < 16) lb[h * N_TOK + n0 + wv * 16 + lane] = lsum;

  const int rn = n0 + wv * 16 + lm;
#pragma unroll
  for (int dt = 0; dt < 4; dt++) {
    bf16x4 ow;
#pragma unroll
    for (int rg = 0; rg < 4; rg++) ow[rg] = (bf16)oacc[dt][rg];
    *(bf16x4*)&pO[(size_t)rn * DIM + h * 64 + dt * 16 + lq * 4] = ow;
  }
}

extern "C" void kernel_launch(void* const* d_in, const int* in_sizes, int n_in,
                              void* d_out, int out_size, void* d_ws, size_t ws_size,
                              hipStream_t stream) {
  const void* x_r     = d_in[0];
  const void* ctx_r   = d_in[1];
  const void* wq_r    = d_in[2];
  const void* bq_r    = d_in[3];
  const void* wk_r    = d_in[4];
  const void* bk_r    = d_in[5];
  const void* wv_r    = d_in[6];
  const void* bv_r    = d_in[7];
  const void* wo_r    = d_in[8];
  const void* bo_r    = d_in[9];
  const void* w1_r    = d_in[10];
  const void* b1_r    = d_in[11];
  const void* w2_r    = d_in[12];
  const void* b2_r    = d_in[13];
  const void* qnw_r   = d_in[14];
  const void* qnb_r   = d_in[15];
  const void* kvnw_r  = d_in[16];
  const void* kvnb_r  = d_in[17];
  const void* pnw_r   = d_in[18];
  const void* pnb_r   = d_in[19];

  // ---- workspace carve: 14M bf16 elems + smalls (~28.0 MB, known-good) ----
  bf16* p = (bf16*)d_ws;
  const size_t MEG = 1024 * 1024;
  bf16* qm  = p;             bf16* hln = qm;
  bf16* km  = p + 2 * MEG;   bf16* xat = km;
  bf16* wC  = p + 4 * MEG;
  bf16* xq  = p + 8 * MEG;   bf16* pO0 = xq;
  bf16* vTb = p + 10 * MEG;
  bf16* kvn = p + 12 * MEG;  bf16* pO1 = kvn;
  bf16* h1h = p + 10 * MEG;  // MLP h1 half spans [10M,14M)
  bf16* SM  = p + 14 * MEG;
  int* flag = (int*)(p + 14 * MEG + 16384);

  bf16* wqT = wC;
  bf16* wkT = wC + 1 * MEG;
  bf16* wvT = wC + 1 * MEG + 786432;
  bf16* woT = wC + 2 * MEG + 524288;
  bf16* w1Th = wC;
  bf16* w2Th = wC + 2 * MEG;
  bf16* w2Ts = p + 8 * MEG;      // shadow w2T-h1 in dead pO0 region (2M elems)
  // l0/l1 in wC tail [3.5M,3.75M): free after woT through o-proj.
  float* l0 = (float*)(wC + 3584 * 1024);
  float* l1 = l0 + N_TOK * 16;   // 32768 floats each

  bf16* bqc = SM, *bkc = SM + 1024, *bvc = SM + 2048, *boc = SM + 3072;
  bf16* b1c = SM + 4096, *b2c = SM + 8192;
  bf16* qnw = SM + 9216, *qnb = SM + 10240;
  bf16* kvnw = SM + 11264, *kvnb = SM + 12032;
  bf16* pnw = SM + 12800, *pnb = SM + 13824;

  // 0) prep: conv + both input LNs + all 4 attention weight transposes
  {
    PrepArgs pa;
    pa.tsrc[0] = wq_r; pa.tdst[0] = wqT; pa.tRcnt[0] = DIM;  pa.tCfull[0] = DIM; pa.tgy[0] = 32;
    pa.tsrc[1] = wk_r; pa.tdst[1] = wkT; pa.tRcnt[1] = CDIM; pa.tCfull[1] = DIM; pa.tgy[1] = 24;
    pa.tsrc[2] = wv_r; pa.tdst[2] = wvT; pa.tRcnt[2] = CDIM; pa.tCfull[2] = DIM; pa.tgy[2] = 24;
    pa.tsrc[3] = wo_r; pa.tdst[3] = woT; pa.tRcnt[3] = DIM;  pa.tCfull[3] = DIM; pa.tgy[3] = 32;
    pa.x = x_r;   pa.qnw = qnw_r;   pa.qnb = qnb_r;   pa.xq = xq;
    pa.ctx = ctx_r; pa.kvnw = kvnw_r; pa.kvnb = kvnb_r; pa.kvn = kvn;
    pa.csrc[0] = bq_r;   pa.cdst[0] = bqc;  pa.cn[0] = DIM;
    pa.csrc[1] = bk_r;   pa.cdst[1] = bkc;  pa.cn[1] = DIM;
    pa.csrc[2] = bv_r;   pa.cdst[2] = bvc;  pa.cn[2] = DIM;
    pa.csrc[3] = bo_r;   pa.cdst[3] = boc;  pa.cn[3] = DIM;
    pa.csrc[4] = b1_r;   pa.cdst[4] = b1c;  pa.cn[4] = DFF;
    pa.csrc[5] = b2_r;   pa.cdst[5] = b2c;  pa.cn[5] = DIM;
    pa.csrc[6] = qnw_r;  pa.cdst[6] = qnw;  pa.cn[6] = DIM;
    pa.csrc[7] = qnb_r;  pa.cdst[7] = qnb;  pa.cn[7] = DIM;
    pa.csrc[8] = kvnw_r; pa.cdst[8] = kvnw; pa.cn[8] = CDIM;
    pa.csrc[9] = kvnb_r; pa.cdst[9] = kvnb; pa.cn[9] = CDIM;
    pa.csrc[10] = pnw_r; pa.cdst[10] = pnw; pa.cn[10] = DIM;
    pa.csrc[11] = pnb_r; pa.cdst[11] = pnb; pa.cn[11] = DIM;
    pa.xprobe = x_r;
    prep_kernel<<<dim3(32, 32, 9), 256, 0, stream>>>(pa, flag);
  }

  // 1) fused q/k/v; z=2 emits V^T directly (A=wvT rows d, Bt=kvn rows m)
  {
    QkvArgs qa;
    qa.A[0] = xq;  qa.Bt[0] = wqT; qa.bias[0] = bqc; qa.C[0] = qm;
    qa.K[0] = DIM;  qa.ldc[0] = DIM;   qa.brow[0] = 0;
    qa.A[1] = kvn; qa.Bt[1] = wkT; qa.bias[1] = bkc; qa.C[1] = km;
    qa.K[1] = CDIM; qa.ldc[1] = DIM;   qa.brow[1] = 0;
    qa.A[2] = wvT; qa.Bt[2] = kvn; qa.bias[2] = bvc; qa.C[2] = vTb;
    qa.K[2] = CDIM; qa.ldc[2] = M_TOK; qa.brow[2] = 1;
    gemm64db_qkv<<<dim3(32, 16, 3), 256, 0, stream>>>(qa);
  }

  // 2) attention split-M (512 attn blocks) + w1-h0 transpose (z2..9)
  attn_kernel<<<dim3(16, 16, 10), 512, 0, stream>>>(qm, km, vTb, pO0, pO1,
                                                    l0, l1, w1_r, w1Th, flag);

  // 3) o-projection with FUSED combine (A = (pO0+pO1)*rinv) + resid(x)
  {
    OprojArgs oa;
    oa.pO0 = pO0; oa.pO1 = pO1; oa.l0 = l0; oa.l1 = l1;
    oa.Bt = woT; oa.bias = boc; oa.resid = x_r; oa.Cout = xat;
    oproj_fused<<<dim3(16, 32), 256, 0, stream>>>(oa, flag);
  }

  // 4) post: post-norm LN + w2-h0 transpose in one launch
  {
    PostArgs po;
    po.w2 = w2_r; po.w2T = w2Th;
    po.xat = xat; po.pnw = pnw_r; po.pnb = pnb_r; po.hln = hln;
    post_kernel<<<dim3(64, 32, 2), 256, 0, stream>>>(po, flag);
  }

  // 5) MLP1 half 0
  gemm64db<2><<<dim3(32, 32), 256, 0, stream>>>(hln, w1Th, b1c, nullptr,
                                                h1h, DIM, 2048, flag);

  // 6) MLP2 half 0 fused with MLP-h1 weight transposes (w2-h1 -> shadow w2Ts)
  {
    Mlp2Args ma;
    ma.h1 = h1h; ma.w2T = w2Th; ma.b2 = b2c; ma.xat = xat; ma.out = d_out;
    ma.w1raw = w1_r; ma.w1Tdst = w1Th;
    ma.w2raw = w2_r; ma.w2Tdst = w2Ts;
    mlp2h0_fused<<<dim3(64, 32, 3), 256, 0, stream>>>(ma, flag);
  }

  // 7) MLP half 1
  gemm64db<2><<<dim3(32, 32), 256, 0, stream>>>(hln, w1Th, b1c + 2048, nullptr,
                                                h1h, DIM, 2048, flag);
  gemm64db<5><<<dim3(16, 32), 256, 0, stream>>>(h1h, w2Ts, b2c, nullptr, d_out,
                                                2048, DIM, flag);
}

// Round 13
// 329.320 us; speedup vs baseline: 1.0295x; 1.0295x over previous
//
#include <hip/hip_runtime.h>

typedef __bf16 bf16;
typedef __bf16 bf16x4 __attribute__((ext_vector_type(4)));
typedef __bf16 bf16x8 __attribute__((ext_vector_type(8)));
typedef float f32x4 __attribute__((ext_vector_type(4)));

#define N_TOK 2048
#define M_TOK 2048
#define DIM 1024
#define CDIM 768
#define DFF 4096

// async global->LDS, 16B per lane; LDS dest = wave-uniform base + lane*16
static __device__ __forceinline__ void async16(const void* g, void* l) {
  __builtin_amdgcn_global_load_lds((const __attribute__((address_space(1))) void*)g,
                                   (__attribute__((address_space(3))) void*)l, 16, 0, 0);
}

// ---------- shared device helpers ----------
// local dtype detect: low-16 halves of first 512 words plausible as bf16?
__device__ __forceinline__ bool detect_bf(const void* xprobe, float* sbuf) {
  int* cnt = (int*)sbuf;
  if (threadIdx.x == 0) *cnt = 0;
  __syncthreads();
  const unsigned* w = (const unsigned*)xprobe;
  int ok = 0;
  for (int i = threadIdx.x; i < 512; i += 256) {
    unsigned lo = w[i] & 0xFFFFu;
    float f = __uint_as_float(lo << 16);
    if (lo == 0u || (fabsf(f) > 1e-3f && fabsf(f) < 1e3f)) ok++;
  }
  atomicAdd(cnt, ok);
  __syncthreads();
  return *cnt >= 256;
}

// 32x32 transpose tile (256 active thr); explicit block coords (bx, by)
__device__ __forceinline__ void t32(int bx, int by, const void* in, bf16* out,
                                    int r0, int Rcnt, int c0, int Cfull,
                                    bool isbf, bf16* t) {
  const int cb = bx * 32, rb = by * 32;
  const int tx = threadIdx.x & 31, ty = threadIdx.x >> 5;
#pragma unroll
  for (int i = 0; i < 4; i++) {
    const size_t r = (size_t)(r0 + rb + ty + i * 8);
    const size_t c = (size_t)(c0 + cb + tx);
    float v = isbf ? (float)((const bf16*)in)[r * Cfull + c]
                   : ((const float*)in)[r * Cfull + c];
    t[(ty + i * 8) * 33 + tx] = (bf16)v;
  }
  __syncthreads();
#pragma unroll
  for (int i = 0; i < 4; i++)
    out[(size_t)(cb + ty + i * 8) * Rcnt + rb + tx] = t[tx * 33 + ty + i * 8];
}

// LayerNorm one row, single global read (row staged in LDS floats).
__device__ __forceinline__ void ln_row(const void* x, const void* wr, const void* br,
                                       bf16* outp, int cols, int row,
                                       bool in_bf, bool w_bf,
                                       float* xrow, float* sh) {
  const bf16* xr_b = (const bf16*)x + (size_t)row * cols;
  const float* xr_f = (const float*)x + (size_t)row * cols;
  bf16* orow = outp + (size_t)row * cols;
  float s = 0.f, ss = 0.f;
  for (int c = threadIdx.x; c < cols; c += 256) {
    float v = in_bf ? (float)xr_b[c] : xr_f[c];
    xrow[c] = v;
    s += v; ss += v * v;
  }
  for (int d = 1; d < 64; d <<= 1) { s += __shfl_xor(s, d, 64); ss += __shfl_xor(ss, d, 64); }
  const int wv = threadIdx.x >> 6, lane = threadIdx.x & 63;
  if (lane == 0) { sh[wv] = s; sh[4 + wv] = ss; }
  __syncthreads();
  s = sh[0] + sh[1] + sh[2] + sh[3];
  ss = sh[4] + sh[5] + sh[6] + sh[7];
  const float mean = s / cols;
  float var = ss / cols - mean * mean;
  var = fmaxf(var, 0.f);
  const float r = rsqrtf(var + 1e-12f);
  for (int c = threadIdx.x; c < cols; c += 256) {
    const float wv2 = w_bf ? (float)((const bf16*)wr)[c] : ((const float*)wr)[c];
    const float bv2 = w_bf ? (float)((const bf16*)br)[c] : ((const float*)br)[c];
    orow[c] = (bf16)((xrow[c] - mean) * r * wv2 + bv2);
  }
}

// ---------------- prep: z0-3 attn-weight transposes, z4-7 input LNs, z8 conv --
struct PrepArgs {
  const void* tsrc[4]; bf16* tdst[4]; int tRcnt[4], tCfull[4], tgy[4];
  const void* x; const void* qnw; const void* qnb; bf16* xq;
  const void* ctx; const void* kvnw; const void* kvnb; bf16* kvn;
  const void* csrc[12]; bf16* cdst[12]; int cn[12];
  const void* xprobe;
};
__global__ __launch_bounds__(256) void prep_kernel(PrepArgs a, int* flag) {
  __shared__ __align__(16) float sbuf[1040];  // union: bf16 t[32*33] | xrow+sh
  const int z = blockIdx.z;
  const bool isbf = detect_bf(a.xprobe, sbuf);
  if (z < 4) {
    if ((int)blockIdx.y >= a.tgy[z]) return;
    t32(blockIdx.x, blockIdx.y, a.tsrc[z], a.tdst[z], 0, a.tRcnt[z], 0, a.tCfull[z],
        isbf, (bf16*)sbuf);
  } else if (z < 8) {
    const int row = blockIdx.x + 32 * blockIdx.y + (z & 1) * 1024;
    if (z < 6) ln_row(a.x,   a.qnw,  a.qnb,  a.xq,  DIM,  row, isbf, isbf, sbuf, sbuf + 1024);
    else       ln_row(a.ctx, a.kvnw, a.kvnb, a.kvn, CDIM, row, isbf, isbf, sbuf, sbuf + 1024);
  } else {
    const int b = blockIdx.x + 32 * blockIdx.y;
    if (b == 0 && threadIdx.x == 0) *flag = isbf ? 1 : 0;
    if (b >= 12) return;
    const void* in = a.csrc[b];
    bf16* out = a.cdst[b];
    const int n = a.cn[b];
    for (int i = threadIdx.x; i < n; i += 256)
      out[i] = isbf ? ((const bf16*)in)[i] : (bf16)((const float*)in)[i];
  }
}

// ---------------- post: z0 w2-h0 T (remapped 32x64), z1 post-norm LN ----------
struct PostArgs {
  const void* w2; bf16* w2T;
  const bf16* xat; const void* pnw; const void* pnb; bf16* hln;
};
__global__ __launch_bounds__(256) void post_kernel(PostArgs a, const int* flag) {
  __shared__ __align__(16) float sbuf[1040];
  const bool isbf = (*flag != 0);
  if (blockIdx.z == 0) {  // w2[0:2048, :] -> w2T [1024][2048]; 32 x 64 via remap
    const int tbx = blockIdx.x & 31, tby = blockIdx.y + 32 * (blockIdx.x >> 5);
    t32(tbx, tby, a.w2, a.w2T, 0, 2048, 0, DIM, isbf, (bf16*)sbuf);
  } else {  // post-norm LN over 2048 rows (input bf16, weights raw)
    const int row = blockIdx.x + 64 * blockIdx.y;
    ln_row(a.xat, a.pnw, a.pnb, a.hln, DIM, row, true, isbf, sbuf, sbuf + 1024);
  }
}

__device__ __forceinline__ float gelu_f(float x) {
  float u = 0.7978845608028654f * (x + 0.044715f * x * x * x);
  return 0.5f * x * (1.f + tanhf(u));
}

// ------ shared epilogue for the 64x64 gemm bodies ------
template <int EPI>
__device__ __forceinline__ void gemm_epi(
    f32x4 (&acc)[2][2], int row0, int col0, int wr, int wc, int lq, int lm,
    const bf16* bias, const void* resid, void* Cout, int ldc, const int* flag) {
  const bool isbf = (*flag != 0);
#pragma unroll
  for (int i = 0; i < 2; i++) {
    const int rb = row0 + wr + i * 16 + lq * 4;
#pragma unroll
    for (int j = 0; j < 2; j++) {
      const int c = col0 + wc + j * 16 + lm;
      const float bv = (EPI != 5) ? (float)bias[c] : 0.f;
#pragma unroll
      for (int rg = 0; rg < 4; rg++) {
        const size_t idx = (size_t)(rb + rg) * ldc + c;
        float v = acc[i][j][rg] + bv;
        if (EPI == 1)
          v += isbf ? (float)((const bf16*)resid)[idx] : ((const float*)resid)[idx];
        if (EPI == 2) v = gelu_f(v);
        if (EPI == 4) v += (float)((const bf16*)resid)[idx];
        if (EPI == 5)
          v += isbf ? (float)((bf16*)Cout)[idx] : ((float*)Cout)[idx];
        if (EPI == 4 || EPI == 5) {
          if (isbf) ((bf16*)Cout)[idx] = (bf16)v;
          else      ((float*)Cout)[idx] = v;
        } else {
          ((bf16*)Cout)[idx] = (bf16)v;
        }
      }
    }
  }
}

// -------- gemm_body: 64x64 tile, BK=64, 256 thr (4 waves 2x2, 32x32/wave) ------
// Harness-verified (rounds 4-10): 2-phase double-buffer + both-sides XOR swizzle.
// (BK=128 variant tried r9: REGRESSED -- 64KB LDS halves blocks/CU; m132 lesson.
//  Combine-fusion into o-proj tried r11: REGRESSED -- reg-staging VALU beats
//  the 4us standalone combine at low occupancy.)
template <int EPI>
__device__ __forceinline__ void gemm_body(
    int bx, int by,
    const bf16* __restrict__ A, const bf16* __restrict__ Bt,
    const bf16* __restrict__ bias, const void* __restrict__ resid,
    void* __restrict__ Cout, int K, int ldc, const int* flag) {
  __shared__ __align__(16) bf16 As[2][64 * 64];
  __shared__ __align__(16) bf16 Bs[2][64 * 64];
  const int tid = threadIdx.x;
  const int lane = tid & 63, wv = tid >> 6;
  const int lq = lane >> 4, lm = lane & 15;
  const int row0 = by * 64, col0 = bx * 64;
  const int wr = (wv >> 1) * 32, wc = (wv & 1) * 32;

  const int sr = lane >> 3;              // staging row within 8-row group
  const int sc = ((lane & 7) ^ sr) * 8;  // pre-swizzled source col (elems)
  const int swz = (lm & 7) << 3;         // read-side XOR (elems)

  f32x4 acc[2][2] = {};

  const bf16* Abase = A + (size_t)(row0 + wv * 16 + sr) * K + sc;
  const bf16* Bbase = Bt + (size_t)(col0 + wv * 16 + sr) * K + sc;

  const int nt = K >> 6;
#pragma unroll
  for (int b = 0; b < 2; b++) {
    async16(Abase + (size_t)(b * 8) * K, &As[0][wv * 1024 + b * 512]);
    async16(Bbase + (size_t)(b * 8) * K, &Bs[0][wv * 1024 + b * 512]);
  }
  __syncthreads();

  int cur = 0;
  for (int t = 0; t < nt; ++t) {
    if (t + 1 < nt) {  // prefetch next tile; loads fly under the MFMA phase
      const int k1 = (t + 1) << 6;
#pragma unroll
      for (int b = 0; b < 2; b++) {
        async16(Abase + (size_t)(b * 8) * K + k1, &As[cur ^ 1][wv * 1024 + b * 512]);
        async16(Bbase + (size_t)(b * 8) * K + k1, &Bs[cur ^ 1][wv * 1024 + b * 512]);
      }
    }
#pragma unroll
    for (int kh = 0; kh < 2; kh++) {
      const int cofs = (kh * 32 + lq * 8) ^ swz;
      bf16x8 af[2], bfv[2];
#pragma unroll
      for (int i = 0; i < 2; i++)
        af[i] = *(const bf16x8*)&As[cur][(wr + i * 16 + lm) * 64 + cofs];
#pragma unroll
      for (int j = 0; j < 2; j++)
        bfv[j] = *(const bf16x8*)&Bs[cur][(wc + j * 16 + lm) * 64 + cofs];
#pragma unroll
      for (int i = 0; i < 2; i++)
#pragma unroll
        for (int j = 0; j < 2; j++)
          acc[i][j] = __builtin_amdgcn_mfma_f32_16x16x32_bf16(af[i], bfv[j], acc[i][j], 0, 0, 0);
    }
    __syncthreads();  // drains prefetch vmcnt + this tile's lgkm reads
    cur ^= 1;
  }
  gemm_epi<EPI>(acc, row0, col0, wr, wc, lq, lm, bias, resid, Cout, ldc, flag);
}

// T1 XCD swizzle: contiguous grid chunks per XCD (all grids have nwg % 8 == 0)
template <int EPI>
__global__ __launch_bounds__(256) void gemm64db(
    const bf16* __restrict__ A, const bf16* __restrict__ Bt,
    const bf16* __restrict__ bias, const void* __restrict__ resid,
    void* __restrict__ Cout, int K, int ldc, const int* flag) {
  const int gx = gridDim.x;
  const int nwg = gx * gridDim.y;
  const int fid = blockIdx.x + gx * blockIdx.y;
  const int sid = (fid & 7) * (nwg >> 3) + (fid >> 3);
  gemm_body<EPI>(sid % gx, sid / gx, A, Bt, bias, resid, Cout, K, ldc, flag);
}

// ---- fused MLP2-h0 gemm + MLP-h1 weight transposes (grid 64x32x3) ----
// z0: gemm<4> (bx<16, XCD-swizzled). z1: w1[:,2048:4096]->w1T (w1T free: its
// reader MLP1-h0 already done). z2: w2[2048:,:]->w2Ts SHADOW, 32x64 via remap.
struct Mlp2Args {
  const bf16* h1; const bf16* w2T; const bf16* b2; const bf16* xat; void* out;
  const void* w1raw; bf16* w1Tdst;
  const void* w2raw; bf16* w2Tdst;
};
__global__ __launch_bounds__(256) void mlp2h0_fused(Mlp2Args a, const int* flag) {
  const int z = blockIdx.z;
  if (z == 0) {
    if ((int)blockIdx.x >= 16) return;
    const int fid = blockIdx.x + 16 * blockIdx.y;  // 512 blocks
    const int sid = (fid & 7) * 64 + (fid >> 3);
    gemm_body<4>(sid & 15, sid >> 4, a.h1, a.w2T, a.b2, a.xat, a.out,
                 2048, DIM, flag);
  } else {
    __shared__ __align__(16) bf16 t[32 * 33];
    const bool isbf = (*flag != 0);
    if (z == 1) {
      t32(blockIdx.x, blockIdx.y, a.w1raw, a.w1Tdst, 0, DIM, 2048, DFF, isbf, t);
    } else {
      const int tbx = blockIdx.x & 31, tby = blockIdx.y + 32 * (blockIdx.x >> 5);
      t32(tbx, tby, a.w2raw, a.w2Tdst, 2048, 2048, 0, DIM, isbf, t);
    }
  }
}

// ------- fused q/k/v projection, z=2 computes V^T directly (bias per row) ------
struct QkvArgs {
  const bf16* A[3];
  const bf16* Bt[3];
  const bf16* bias[3];
  bf16* C[3];
  int K[3], ldc[3], brow[3];
};
__global__ __launch_bounds__(256) void gemm64db_qkv(QkvArgs a) {
  const int z = blockIdx.z;
  int gx, bx0, by0;
  if (z < 2) { gx = 16; bx0 = blockIdx.y; by0 = blockIdx.x; }   // 16c x 32r
  else       { gx = 32; bx0 = blockIdx.x; by0 = blockIdx.y; }   // 32c x 16r
  const int fid = bx0 + gx * by0;                                // 512 blocks
  const int sid = (fid & 7) * 64 + (fid >> 3);
  const int bx = sid % gx, by = sid / gx;
  const bf16* A = a.A[z];
  const bf16* Bt = a.Bt[z];
  const int K = a.K[z];
  __shared__ __align__(16) bf16 As[2][64 * 64];
  __shared__ __align__(16) bf16 Bs[2][64 * 64];
  const int tid = threadIdx.x;
  const int lane = tid & 63, wv = tid >> 6;
  const int lq = lane >> 4, lm = lane & 15;
  const int row0 = by * 64, col0 = bx * 64;
  const int wr = (wv >> 1) * 32, wc = (wv & 1) * 32;

  const int sr = lane >> 3;
  const int sc = ((lane & 7) ^ sr) * 8;
  const int swz = (lm & 7) << 3;

  f32x4 acc[2][2] = {};

  const bf16* Abase = A + (size_t)(row0 + wv * 16 + sr) * K + sc;
  const bf16* Bbase = Bt + (size_t)(col0 + wv * 16 + sr) * K + sc;

  const int nt = K >> 6;
#pragma unroll
  for (int b = 0; b < 2; b++) {
    async16(Abase + (size_t)(b * 8) * K, &As[0][wv * 1024 + b * 512]);
    async16(Bbase + (size_t)(b * 8) * K, &Bs[0][wv * 1024 + b * 512]);
  }
  __syncthreads();

  int cur = 0;
  for (int t = 0; t < nt; ++t) {
    if (t + 1 < nt) {
      const int k1 = (t + 1) << 6;
#pragma unroll
      for (int b = 0; b < 2; b++) {
        async16(Abase + (size_t)(b * 8) * K + k1, &As[cur ^ 1][wv * 1024 + b * 512]);
        async16(Bbase + (size_t)(b * 8) * K + k1, &Bs[cur ^ 1][wv * 1024 + b * 512]);
      }
    }
#pragma unroll
    for (int kh = 0; kh < 2; kh++) {
      const int cofs = (kh * 32 + lq * 8) ^ swz;
      bf16x8 af[2], bfv[2];
#pragma unroll
      for (int i = 0; i < 2; i++)
        af[i] = *(const bf16x8*)&As[cur][(wr + i * 16 + lm) * 64 + cofs];
#pragma unroll
      for (int j = 0; j < 2; j++)
        bfv[j] = *(const bf16x8*)&Bs[cur][(wc + j * 16 + lm) * 64 + cofs];
#pragma unroll
      for (int i = 0; i < 2; i++)
#pragma unroll
        for (int j = 0; j < 2; j++)
          acc[i][j] = __builtin_amdgcn_mfma_f32_16x16x32_bf16(af[i], bfv[j], acc[i][j], 0, 0, 0);
    }
    __syncthreads();
    cur ^= 1;
  }

  const bf16* bias = a.bias[z];
  bf16* C = a.C[z];
  const int ldc = a.ldc[z];
  const bool brow = a.brow[z] != 0;
#pragma unroll
  for (int i = 0; i < 2; i++) {
    const int rb = row0 + wr + i * 16 + lq * 4;
#pragma unroll
    for (int j = 0; j < 2; j++) {
      const int c = col0 + wc + j * 16 + lm;
      const float bcol = brow ? 0.f : (float)bias[c];
#pragma unroll
      for (int rg = 0; rg < 4; rg++) {
        const float bv = brow ? (float)bias[rb + rg] : bcol;
        C[(size_t)(rb + rg) * ldc + c] = (bf16)(acc[i][j][rg] + bv);
      }
    }
  }
}

// ---------------- Flash attention v13: global_load_lds staging ----------------
// K/V staged via async16 (zero VALU round-trip): linear LDS dest + pre-swizzled
// per-lane SOURCE col (both-sides rule). Verified r9/r10.
// z0,z1: attention halves. z2..9: w1-h0 transpose (aliases KPs).
__global__ __launch_bounds__(512) void attn_kernel(
    const bf16* __restrict__ q, const bf16* __restrict__ k,
    const bf16* __restrict__ vT, bf16* __restrict__ pO0, bf16* __restrict__ pO1,
    float* __restrict__ l0, float* __restrict__ l1,
    const void* __restrict__ w1raw, bf16* __restrict__ w1Tdst,
    const int* __restrict__ flag) {
  __shared__ __align__(16) bf16 KPs[128 * 128];  // Ks [128][64]; then P^T [128][128]
  __shared__ __align__(16) bf16 Vs[64 * 128];    // [d 64][m 128]
  const int z = blockIdx.z;
  if (z >= 2) {  // w1-h0 transpose: 2048 blocks over z=2..9
    if (threadIdx.x >= 256) return;  // waves 4-7 exit (wave-aligned)
    const int id = blockIdx.x + 16 * blockIdx.y + 256 * (z - 2);
    const bool isbf = (*flag != 0);
    t32(id & 63, id >> 6, w1raw, w1Tdst, 0, DIM, 0, DFF, isbf, (bf16*)KPs);
    return;
  }
  const int tid = threadIdx.x, lane = tid & 63, wv = tid >> 6;
  const int lq = lane >> 4, lm = lane & 15;
  // XCD-aware bijective swizzle (512 = 8*64): XCD j gets 4 whole heads (1 half).
  const int fid = blockIdx.x + 16 * (blockIdx.y + 16 * z);
  const int sid = (fid & 7) * 64 + (fid >> 3);
  const int n0 = (sid & 15) * 128;
  const int h = (sid >> 4) & 15;
  const int half = sid >> 8;
  const int mbeg = half * (M_TOK / 2), mend = mbeg + M_TOK / 2;
  bf16* pO = half ? pO1 : pO0;
  float* lb = half ? l1 : l0;

  bf16x8 qf[2];
#pragma unroll
  for (int f = 0; f < 2; f++)
    qf[f] = *(const bf16x8*)&q[(size_t)(n0 + wv * 16 + lm) * DIM + h * 64 + f * 32 + lq * 8];

  f32x4 oacc[4] = {};  // O^T tiles: rows d, cols n (n-col = wv*16+lm)
  float lsum = 0.f;
  const float sc = 0.125f * 1.4426950408889634f;  // (1/sqrt(64)) * log2(e)

  // per-lane pre-swizzled staging sources (loop-invariant)
  const int l3 = lane >> 3, l4 = lane >> 4;
  const bf16* kb = k + (size_t)(wv * 16 + l3) * DIM + h * 64 + (((lane & 7) ^ l3) << 3);
  const bf16* vb0 = vT + (size_t)(h * 64 + wv * 8 + l4) * M_TOK + (((lane & 15) ^ l4) << 3);
  const bf16* vb1 = vT + (size_t)(h * 64 + wv * 8 + 4 + l4) * M_TOK + (((lane & 15) ^ (4 + l4)) << 3);
  bf16* kd = KPs + wv * 1024;  // wave-uniform dest (rows wv*16..+16 of [128][64])
  bf16* vd = Vs + wv * 1024;   // rows wv*8..+8 of [64][128]

  for (int m0 = mbeg; m0 < mend; m0 += 128) {
    __syncthreads();  // prev tile fully consumed (P^T + V PV reads done)
    {
      const bf16* kt = kb + (size_t)m0 * DIM;
      async16(kt, kd);
      async16(kt + (size_t)8 * DIM, kd + 512);
      async16(vb0 + m0, vd);
      async16(vb1 + m0, vd + 512);
    }
    __syncthreads();  // drains vmcnt(0) -> tile visible in LDS

    // S^T into regs: tile j rows m = j*16+lq*4+rg, col n = wv*16 + lm
    f32x4 s[8];
    __builtin_amdgcn_s_setprio(1);
#pragma unroll
    for (int j = 0; j < 8; j++) {
      const int kswz = (lm & 7) << 3;  // row = j*16+lm -> row&7 = lm&7
      bf16x8 kf0 = *(const bf16x8*)&KPs[(j * 16 + lm) * 64 + ((lq * 8) ^ kswz)];
      bf16x8 kf1 = *(const bf16x8*)&KPs[(j * 16 + lm) * 64 + ((32 + lq * 8) ^ kswz)];
      f32x4 zz = {};
      zz = __builtin_amdgcn_mfma_f32_16x16x32_bf16(kf0, qf[0], zz, 0, 0, 0);
      s[j] = __builtin_amdgcn_mfma_f32_16x16x32_bf16(kf1, qf[1], zz, 0, 0, 0);
    }
    __builtin_amdgcn_s_setprio(0);
    asm volatile("s_waitcnt lgkmcnt(0)" ::: "memory");
    __builtin_amdgcn_s_barrier();  // Ks region free -> becomes P^T [128][128]

#pragma unroll
    for (int j = 0; j < 8; j++) {
      bf16x4 pw;
#pragma unroll
      for (int rg = 0; rg < 4; rg++) {
        const float pv = exp2f(s[j][rg] * sc);
        lsum += pv;
        pw[rg] = (bf16)pv;
      }
      // P^T row n = wv*16+lm (row&7 = lm&7), col m = j*16+lq*4; swizzled write
      *(bf16x4*)&KPs[(wv * 16 + lm) * 128 + ((j * 16 + lq * 4) ^ ((lm & 7) << 3))] = pw;
    }

    // O^T += V^T P^T (pf rows are this wave's own -> same-wave RAW, lgkmcnt)
    __builtin_amdgcn_s_setprio(1);
#pragma unroll
    for (int kk = 0; kk < 4; kk++) {
      bf16x8 pf = *(const bf16x8*)&KPs[(wv * 16 + lm) * 128 +
                                       ((kk * 32 + lq * 8) ^ ((lm & 7) << 3))];
#pragma unroll
      for (int dt = 0; dt < 4; dt++) {
        bf16x8 vf = *(const bf16x8*)&Vs[(dt * 16 + lm) * 128 +
                                        ((kk * 32 + lq * 8) ^ ((lm & 7) << 3))];
        oacc[dt] = __builtin_amdgcn_mfma_f32_16x16x32_bf16(vf, pf, oacc[dt], 0, 0, 0);
      }
    }
    __builtin_amdgcn_s_setprio(0);
  }

  // partial row-sum: reduce over the 4 lanes sharing this n (lane bits 4..5)
  lsum += __shfl_xor(lsum, 16, 64);
  lsum += __shfl_xor(lsum, 32, 64);
  if (lane < 16) lb[h * N_TOK + n0 + wv * 16 + lane] = lsum;

  const int rn = n0 + wv * 16 + lm;
#pragma unroll
  for (int dt = 0; dt < 4; dt++) {
    bf16x4 ow;
#pragma unroll
    for (int rg = 0; rg < 4; rg++) ow[rg] = (bf16)oacc[dt][rg];
    *(bf16x4*)&pO[(size_t)rn * DIM + h * 64 + dt * 16 + lq * 4] = ow;
  }
}

// ---------------- combine: om = (pO0 + pO1) / (l0 + l1) ----------------
__global__ __launch_bounds__(256) void attn_combine(
    const bf16* __restrict__ pO0, const bf16* __restrict__ pO1,
    const float* __restrict__ l0, const float* __restrict__ l1,
    bf16* __restrict__ om) {
  const int i4 = (blockIdx.x * 256 + threadIdx.x) * 4;  // over N*DIM = 2M elems
  const int n = i4 >> 10;
  const int h = (i4 & 1023) >> 6;
  const float rinv = 1.f / (l0[h * N_TOK + n] + l1[h * N_TOK + n]);
  bf16x4 a = *(const bf16x4*)&pO0[i4];
  bf16x4 b = *(const bf16x4*)&pO1[i4];
  bf16x4 o;
#pragma unroll
  for (int r = 0; r < 4; r++) o[r] = (bf16)(((float)a[r] + (float)b[r]) * rinv);
  *(bf16x4*)&om[i4] = o;
}

extern "C" void kernel_launch(void* const* d_in, const int* in_sizes, int n_in,
                              void* d_out, int out_size, void* d_ws, size_t ws_size,
                              hipStream_t stream) {
  const void* x_r     = d_in[0];
  const void* ctx_r   = d_in[1];
  const void* wq_r    = d_in[2];
  const void* bq_r    = d_in[3];
  const void* wk_r    = d_in[4];
  const void* bk_r    = d_in[5];
  const void* wv_r    = d_in[6];
  const void* bv_r    = d_in[7];
  const void* wo_r    = d_in[8];
  const void* bo_r    = d_in[9];
  const void* w1_r    = d_in[10];
  const void* b1_r    = d_in[11];
  const void* w2_r    = d_in[12];
  const void* b2_r    = d_in[13];
  const void* qnw_r   = d_in[14];
  const void* qnb_r   = d_in[15];
  const void* kvnw_r  = d_in[16];
  const void* kvnb_r  = d_in[17];
  const void* pnw_r   = d_in[18];
  const void* pnb_r   = d_in[19];

  // ---- workspace carve: 14M bf16 elems + smalls (~28.0 MB, known-good) ----
  bf16* p = (bf16*)d_ws;
  const size_t MEG = 1024 * 1024;
  bf16* qm  = p;             bf16* hln = qm;
  bf16* km  = p + 2 * MEG;   bf16* xat = km;
  bf16* wC  = p + 4 * MEG;
  bf16* xq  = p + 8 * MEG;   bf16* pO0 = xq;   bf16* om = xq;
  bf16* vTb = p + 10 * MEG;
  bf16* kvn = p + 12 * MEG;  bf16* pO1 = kvn;
  bf16* h1h = p + 10 * MEG;  // MLP h1 half spans [10M,14M)
  bf16* SM  = p + 14 * MEG;
  int* flag = (int*)(p + 14 * MEG + 16384);

  bf16* wqT = wC;
  bf16* wkT = wC + 1 * MEG;
  bf16* wvT = wC + 1 * MEG + 786432;
  bf16* woT = wC + 2 * MEG + 524288;
  bf16* w1Th = wC;
  bf16* w2Th = wC + 2 * MEG;
  bf16* w2Ts = p + 8 * MEG;      // shadow w2T-h1 in dead om region (2M elems)
  // l0/l1 in wC tail [3.5M,3.75M): free after woT through combine.
  float* l0 = (float*)(wC + 3584 * 1024);
  float* l1 = l0 + N_TOK * 16;   // 32768 floats each

  bf16* bqc = SM, *bkc = SM + 1024, *bvc = SM + 2048, *boc = SM + 3072;
  bf16* b1c = SM + 4096, *b2c = SM + 8192;
  bf16* qnw = SM + 9216, *qnb = SM + 10240;
  bf16* kvnw = SM + 11264, *kvnb = SM + 12032;
  bf16* pnw = SM + 12800, *pnb = SM + 13824;

  // 0) prep: conv + both input LNs + all 4 attention weight transposes
  {
    PrepArgs pa;
    pa.tsrc[0] = wq_r; pa.tdst[0] = wqT; pa.tRcnt[0] = DIM;  pa.tCfull[0] = DIM; pa.tgy[0] = 32;
    pa.tsrc[1] = wk_r; pa.tdst[1] = wkT; pa.tRcnt[1] = CDIM; pa.tCfull[1] = DIM; pa.tgy[1] = 24;
    pa.tsrc[2] = wv_r; pa.tdst[2] = wvT; pa.tRcnt[2] = CDIM; pa.tCfull[2] = DIM; pa.tgy[2] = 24;
    pa.tsrc[3] = wo_r; pa.tdst[3] = woT; pa.tRcnt[3] = DIM;  pa.tCfull[3] = DIM; pa.tgy[3] = 32;
    pa.x = x_r;   pa.qnw = qnw_r;   pa.qnb = qnb_r;   pa.xq = xq;
    pa.ctx = ctx_r; pa.kvnw = kvnw_r; pa.kvnb = kvnb_r; pa.kvn = kvn;
    pa.csrc[0] = bq_r;   pa.cdst[0] = bqc;  pa.cn[0] = DIM;
    pa.csrc[1] = bk_r;   pa.cdst[1] = bkc;  pa.cn[1] = DIM;
    pa.csrc[2] = bv_r;   pa.cdst[2] = bvc;  pa.cn[2] = DIM;
    pa.csrc[3] = bo_r;   pa.cdst[3] = boc;  pa.cn[3] = DIM;
    pa.csrc[4] = b1_r;   pa.cdst[4] = b1c;  pa.cn[4] = DFF;
    pa.csrc[5] = b2_r;   pa.cdst[5] = b2c;  pa.cn[5] = DIM;
    pa.csrc[6] = qnw_r;  pa.cdst[6] = qnw;  pa.cn[6] = DIM;
    pa.csrc[7] = qnb_r;  pa.cdst[7] = qnb;  pa.cn[7] = DIM;
    pa.csrc[8] = kvnw_r; pa.cdst[8] = kvnw; pa.cn[8] = CDIM;
    pa.csrc[9] = kvnb_r; pa.cdst[9] = kvnb; pa.cn[9] = CDIM;
    pa.csrc[10] = pnw_r; pa.cdst[10] = pnw; pa.cn[10] = DIM;
    pa.csrc[11] = pnb_r; pa.cdst[11] = pnb; pa.cn[11] = DIM;
    pa.xprobe = x_r;
    prep_kernel<<<dim3(32, 32, 9), 256, 0, stream>>>(pa, flag);
  }

  // 1) fused q/k/v; z=2 emits V^T directly (A=wvT rows d, Bt=kvn rows m)
  {
    QkvArgs qa;
    qa.A[0] = xq;  qa.Bt[0] = wqT; qa.bias[0] = bqc; qa.C[0] = qm;
    qa.K[0] = DIM;  qa.ldc[0] = DIM;   qa.brow[0] = 0;
    qa.A[1] = kvn; qa.Bt[1] = wkT; qa.bias[1] = bkc; qa.C[1] = km;
    qa.K[1] = CDIM; qa.ldc[1] = DIM;   qa.brow[1] = 0;
    qa.A[2] = wvT; qa.Bt[2] = kvn; qa.bias[2] = bvc; qa.C[2] = vTb;
    qa.K[2] = CDIM; qa.ldc[2] = M_TOK; qa.brow[2] = 1;
    gemm64db_qkv<<<dim3(32, 16, 3), 256, 0, stream>>>(qa);
  }

  // 2) attention split-M (512 attn blocks) + w1-h0 transpose (z2..9) + combine
  attn_kernel<<<dim3(16, 16, 10), 512, 0, stream>>>(qm, km, vTb, pO0, pO1,
                                                    l0, l1, w1_r, w1Th, flag);
  attn_combine<<<2048, 256, 0, stream>>>(pO0, pO1, l0, l1, om);

  // 3) o-projection + raw-dtype residual(x)
  gemm64db<1><<<dim3(16, 32), 256, 0, stream>>>(om, woT, boc, x_r, xat, DIM, DIM, flag);

  // 4) post: post-norm LN + w2-h0 transpose in one launch
  {
    PostArgs po;
    po.w2 = w2_r; po.w2T = w2Th;
    po.xat = xat; po.pnw = pnw_r; po.pnb = pnb_r; po.hln = hln;
    post_kernel<<<dim3(64, 32, 2), 256, 0, stream>>>(po, flag);
  }

  // 5) MLP1 half 0
  gemm64db<2><<<dim3(32, 32), 256, 0, stream>>>(hln, w1Th, b1c, nullptr,
                                                h1h, DIM, 2048, flag);

  // 6) MLP2 half 0 fused with MLP-h1 weight transposes (w2-h1 -> shadow w2Ts)
  {
    Mlp2Args ma;
    ma.h1 = h1h; ma.w2T = w2Th; ma.b2 = b2c; ma.xat = xat; ma.out = d_out;
    ma.w1raw = w1_r; ma.w1Tdst = w1Th;
    ma.w2raw = w2_r; ma.w2Tdst = w2Ts;
    mlp2h0_fused<<<dim3(64, 32, 3), 256, 0, stream>>>(ma, flag);
  }

  // 7) MLP half 1
  gemm64db<2><<<dim3(32, 32), 256, 0, stream>>>(hln, w1Th, b1c + 2048, nullptr,
                                                h1h, DIM, 2048, flag);
  gemm64db<5><<<dim3(16, 32), 256, 0, stream>>>(h1h, w2Ts, b2c, nullptr, d_out,
                                                2048, DIM, flag);
}